// Round 10
// baseline (334.857 us; speedup 1.0000x reference)
//
#include <hip/hip_runtime.h>
#include <hip/hip_bf16.h>

// SOBA-Monarch, B*H=64 heads, S=4096, D=64, nb=bs=64, pad=0, 3 steps.
// Round 10 = R9 swapped-MM1/in-lane-softmax + R4 LDS-staged flush +
//   XCD-aware bijective swizzle (head-per-XCD L2 locality) +
//   native bf16 cvt for all split/pack + contiguous alpha/tau writes.
// Layouts: G [h][j][k][v] u32 | Hm,Y [h][k][j][v] u32 | M [h][j][v] u32
//          alpha [h][k][j] f32 (bc contig write) | tau [h][j][k] f32 (da contig write)

namespace {

typedef __attribute__((ext_vector_type(8))) short short8v;
typedef __attribute__((ext_vector_type(4))) float f32x4;

constexpr int HEADS = 64;
constexpr size_t HEADQ = 262144;                 // 4096*64 per head
constexpr size_t MATF  = (size_t)HEADS * 262144;

#define MFMA(ACC, A, B) ACC = __builtin_amdgcn_mfma_f32_16x16x32_bf16(A, B, ACC, 0, 0, 0)
#define LD8(arr, row, g8) (*(const short8v*)((arr) + (row) * 72 + (g8) * 8))

__device__ __forceinline__ ushort bfh(float x) {
    return __builtin_bit_cast(ushort, __float2bfloat16(x));   // native RNE cvt
}
__device__ __forceinline__ float bf2f(ushort h) {
    return __uint_as_float(((uint)h) << 16);
}
__device__ __forceinline__ void bfsplit(float x, ushort& h, ushort& l) {
    h = bfh(x);
    l = bfh(x - bf2f(h));
}
__device__ __forceinline__ uint packbf(float x) {
    ushort h, l; bfsplit(x, h, l);
    return ((uint)h << 16) | l;
}

struct Frag16 { short8v h0, h1, l0, l1; };

// f32 global (16 elems) -> split regs
__device__ __forceinline__ Frag16 split_load(const float* __restrict__ p, float s) {
    Frag16 f;
    #pragma unroll
    for (int q = 0; q < 4; ++q) {
        float4 a = *(const float4*)(p + 4 * q);
        float v[4] = {a.x * s, a.y * s, a.z * s, a.w * s};
        #pragma unroll
        for (int e = 0; e < 4; ++e) {
            ushort hh, ll; bfsplit(v[e], hh, ll);
            const int i = 4 * q + e;
            if (i < 8) { f.h0[i] = (short)hh; f.l0[i] = (short)ll; }
            else       { f.h1[i - 8] = (short)hh; f.l1[i - 8] = (short)ll; }
        }
    }
    return f;
}
// packed-u32 global -> split regs (2 ops/elem)
__device__ __forceinline__ Frag16 unpack_load(const uint* __restrict__ p) {
    Frag16 f;
    #pragma unroll
    for (int q = 0; q < 2; ++q) {
        uint4 a = *(const uint4*)(p + 8 * q);
        uint4 b = *(const uint4*)(p + 8 * q + 4);
        uint vv[8] = {a.x, a.y, a.z, a.w, b.x, b.y, b.z, b.w};
        short8v h, l;
        #pragma unroll
        for (int e = 0; e < 8; ++e) {
            h[e] = (short)(vv[e] >> 16);
            l[e] = (short)(vv[e] & 0xFFFFu);
        }
        if (q == 0) { f.h0 = h; f.l0 = l; } else { f.h1 = h; f.l1 = l; }
    }
    return f;
}
__device__ __forceinline__ void store_rows(ushort* H, ushort* L, int r, int c0,
                                           const Frag16& f) {
    *(short8v*)(H + r * 72 + c0)     = f.h0;
    *(short8v*)(H + r * 72 + c0 + 8) = f.h1;
    *(short8v*)(L + r * 72 + c0)     = f.l0;
    *(short8v*)(L + r * 72 + c0 + 8) = f.l1;
}
__device__ __forceinline__ void scatter_tr(ushort* H, ushort* L, int r, int c0,
                                           const Frag16& f) {
    #pragma unroll
    for (int e = 0; e < 8; ++e) {
        H[(c0 + e) * 72 + r] = (ushort)f.h0[e];
        L[(c0 + e) * 72 + r] = (ushort)f.l0[e];
    }
    #pragma unroll
    for (int e = 0; e < 8; ++e) {
        H[(c0 + 8 + e) * 72 + r] = (ushort)f.h1[e];
        L[(c0 + 8 + e) * 72 + r] = (ushort)f.l1[e];
    }
}

// flush staged [64][68] u32 tile -> contiguous 16KB global block
__device__ __forceinline__ void flush_u32(const uint* OS, uint* g, int tid) {
    #pragma unroll
    for (int q = 0; q < 4; ++q) {
        const int off = tid * 4 + q * 1024;
        uint4 v = *(const uint4*)(OS + (off >> 6) * 68 + (off & 63));
        *(uint4*)(g + off) = v;
    }
}

__device__ __forceinline__ void mmstep(const ushort* AH, const ushort* AL,
                                       const ushort* BH, const ushort* BL,
                                       int w, int lo4, int hi4, f32x4 acc[4]) {
    #pragma unroll
    for (int ks = 0; ks < 2; ++ks) {
        short8v ah = LD8(AH, 16 * w + lo4, hi4 + 4 * ks);
        short8v al = LD8(AL, 16 * w + lo4, hi4 + 4 * ks);
        #pragma unroll
        for (int t = 0; t < 4; ++t) {
            short8v bh = LD8(BH, 16 * t + lo4, hi4 + 4 * ks);
            short8v bl = LD8(BL, 16 * t + lo4, hi4 + 4 * ks);
            MFMA(acc[t], ah, bh); MFMA(acc[t], ah, bl); MFMA(acc[t], al, bh);
        }
    }
}
// swapped: acc[m] = A-strip m (from B region) x B-strip w (from A region)
__device__ __forceinline__ void mmstep_swap(const ushort* AH, const ushort* AL,
                                            const ushort* BH, const ushort* BL,
                                            int w, int lo4, int hi4, f32x4 acc[4]) {
    #pragma unroll
    for (int ks = 0; ks < 2; ++ks) {
        short8v bh = LD8(AH, 16 * w + lo4, hi4 + 4 * ks);
        short8v bl = LD8(AL, 16 * w + lo4, hi4 + 4 * ks);
        #pragma unroll
        for (int m = 0; m < 4; ++m) {
            short8v ah = LD8(BH, 16 * m + lo4, hi4 + 4 * ks);
            short8v al = LD8(BL, 16 * m + lo4, hi4 + 4 * ks);
            MFMA(acc[m], ah, bh); MFMA(acc[m], ah, bl); MFMA(acc[m], al, bh);
        }
    }
}

__device__ __forceinline__ float max16(const float* x) {
    float a = fmaxf(fmaxf(x[0], x[1]), fmaxf(x[2], x[3]));
    float b = fmaxf(fmaxf(x[4], x[5]), fmaxf(x[6], x[7]));
    float c = fmaxf(fmaxf(x[8], x[9]), fmaxf(x[10], x[11]));
    float d = fmaxf(fmaxf(x[12], x[13]), fmaxf(x[14], x[15]));
    return fmaxf(fmaxf(a, b), fmaxf(c, d));
}
__device__ __forceinline__ float sum16(const float* x) {
    float a = (x[0] + x[1]) + (x[2] + x[3]);
    float b = (x[4] + x[5]) + (x[6] + x[7]);
    float c = (x[8] + x[9]) + (x[10] + x[11]);
    float d = (x[12] + x[13]) + (x[14] + x[15]);
    return (a + b) + (c + d);
}

// XCD-aware bijective swizzle (4096 = 8 x 512; 1024 = 8 x 128)
__device__ __forceinline__ int swz_wg(int bid, int chunk) {
    return (bid & 7) * chunk + (bid >> 3);
}

// M[h][j][v] = packbf( (1/512) * sum_l Q[h][l*64+j][v] )
__global__ __launch_bounds__(256) void kmean_kernel(const float* __restrict__ Q,
                                                    uint* __restrict__ M) {
    const int wg = swz_wg(blockIdx.x, 128);         // 1024 WGs
    const int h  = wg >> 4;
    const int j  = ((wg & 15) << 2) + (threadIdx.x >> 6);
    const int v  = threadIdx.x & 63;
    const float* base = Q + (size_t)h * HEADQ + (size_t)j * 64 + v;
    float acc = 0.f;
    #pragma unroll
    for (int l = 0; l < 64; ++l) acc += base[(size_t)l * 4096];
    M[((size_t)h * 64 + j) * 64 + v] = packbf(acc * (1.0f / 512.0f));
}

// One WG (256T) per (h,k).
// MM1 (swapped): beta^T[i,j]; in-lane softmax over i; alpha[j] contiguous write
// MM2: Hm[j,v]=sum_i right[j,i]K[i,v];  LAST: Y[j,v]=sum_i right[j,i]V[i,v]
template<int FIRST, int LAST>
__global__ __launch_bounds__(256, 4) void bc_kernel(
    const uint*  __restrict__ Gsrc,   // FIRST ? M[h][j][v] : G[h][j][k][v]
    const float* __restrict__ Kmat,
    const float* __restrict__ Vmat,   // LAST only
    const float* __restrict__ tauIn,  // !FIRST, [h][j][k]
    uint*  __restrict__ HmOut,        // [h][k][j][v] packed
    float* __restrict__ alphaOut,     // [h][k][j]
    uint*  __restrict__ Yout)         // LAST only, [h][k][j][v] packed
{
    __shared__ __align__(16) ushort SM[18432];     // 36864 B -> 4 WG/CU
    ushort* Ah = SM;          ushort* Al = SM + 4608;   // G rows -> right rows
    ushort* Bh = SM + 9216;   ushort* Bl = SM + 13824;  // K rows -> K^T -> V^T
    uint* OSA = (uint*)SM;                              // staging over A (17408 B)
    uint* OSB = (uint*)(SM + 9216);                     // staging over B

    const int wg = swz_wg(blockIdx.x, 512), h = wg >> 6, k = wg & 63;
    const int tid = threadIdx.x, r = tid & 63, c0 = (tid >> 6) << 4;
    const int w = tid >> 6, lo4 = tid & 15, hi4 = (tid >> 4) & 3;

    { // stage G rows -> A (cheap unpack)
        const uint* gp = FIRST ? Gsrc + ((size_t)h * 64 + r) * 64 + c0
                               : Gsrc + ((size_t)h * 64 + r) * 4096 + (size_t)k * 64 + c0;
        store_rows(Ah, Al, r, c0, unpack_load(gp));
    }
    // stage K rows -> B, keep regs for K^T scatter
    Frag16 fk = split_load(Kmat + (size_t)h * HEADQ + (size_t)k * 4096 + r * 64 + c0, 1.f);
    store_rows(Bh, Bl, r, c0, fk);
    Frag16 fv;
    if (LAST)
        fv = split_load(Vmat + (size_t)h * HEADQ + (size_t)k * 4096 + r * 64 + c0, 1.f);
    // tau: one scalar per lane (j = 16w + lo4), [h][j][k] gather (L2-hot)
    float tv = 1.f;
    if (!FIRST) tv = tauIn[((size_t)h * 64 + 16 * w + lo4) * 64 + k];
    __syncthreads();

    // MM1 swapped: acc[m][reg] = beta[i=16m+4hi4+reg][j=16w+lo4]
    f32x4 acc[4] = {};
    mmstep_swap(Ah, Al, Bh, Bl, w, lo4, hi4, acc);
    __syncthreads();

    // softmax over i: in-lane 16 + shfl_xor(16,32); per-lane j
    {
        const int j = 16 * w + lo4;
        const bool tz = !(tv > 1e-8f);
        const float tvi = tz ? 1.f : 1.f / tv;
        float x[16];
        #pragma unroll
        for (int m = 0; m < 4; ++m)
            #pragma unroll
            for (int rg = 0; rg < 4; ++rg) x[4 * m + rg] = acc[m][rg] * tvi;
        float mx = max16(x);
        mx = fmaxf(mx, __shfl_xor(mx, 16));
        mx = fmaxf(mx, __shfl_xor(mx, 32));
        #pragma unroll
        for (int e = 0; e < 16; ++e) x[e] = __expf(x[e] - mx);
        float s = sum16(x);
        s += __shfl_xor(s, 16);
        s += __shfl_xor(s, 32);
        const float inv = 1.f / s;
        float ap = 0.f;
        #pragma unroll
        for (int m = 0; m < 4; ++m) {
            #pragma unroll
            for (int rg = 0; rg < 4; ++rg) {
                const float rv = tz ? (1.f / 64.f) : x[4 * m + rg] * inv;
                ap += (rv > 0.f) ? rv * __logf(rv) : 0.f;
                ushort hh, ll; bfsplit(rv, hh, ll);
                const int i = 16 * m + 4 * hi4 + rg;
                Ah[j * 72 + i] = hh;                 // right rows [j][i]
                Al[j * 72 + i] = ll;
            }
        }
        ap += __shfl_xor(ap, 16);
        ap += __shfl_xor(ap, 32);
        if (hi4 == 0) alphaOut[((size_t)h * 64 + k) * 64 + j] = ap;  // contiguous
    }
    scatter_tr(Bh, Bl, r, c0, fk);                 // K^T over dead K rows
    __syncthreads();

    f32x4 acc2[4] = {};
    mmstep(Ah, Al, Bh, Bl, w, lo4, hi4, acc2);     // Hm: A=right rows, B=K^T
    const size_t ob = ((size_t)h * 64 + k) * 4096;
    if (!LAST) {
        __syncthreads();
        #pragma unroll
        for (int rr = 0; rr < 4; ++rr) {           // stage Hm packed -> OSB
            const int j = 16 * w + 4 * hi4 + rr;
            #pragma unroll
            for (int t = 0; t < 4; ++t)
                OSB[j * 68 + 16 * t + lo4] = packbf(acc2[t][rr]);
        }
        __syncthreads();
        flush_u32(OSB, HmOut + ob, tid);
    } else {
        __syncthreads();
        scatter_tr(Bh, Bl, r, c0, fv);             // V^T over dead K^T
        __syncthreads();
        f32x4 acc3[4] = {};
        mmstep(Ah, Al, Bh, Bl, w, lo4, hi4, acc3); // Y: A=right, B=V^T
        __syncthreads();
        #pragma unroll
        for (int rr = 0; rr < 4; ++rr) {           // stage Hm -> OSA, Y -> OSB
            const int j = 16 * w + 4 * hi4 + rr;
            #pragma unroll
            for (int t = 0; t < 4; ++t) {
                OSA[j * 68 + 16 * t + lo4] = packbf(acc2[t][rr]);
                OSB[j * 68 + 16 * t + lo4] = packbf(acc3[t][rr]);
            }
        }
        __syncthreads();
        flush_u32(OSA, HmOut + ob, tid);
        flush_u32(OSB, Yout + ob, tid);
    }
}

// One WG per (h,j).
// MM1 (swapped): beta2^T[k,l]; in-lane softmax over k
// !LAST: G[k,v]=sum_l left[l,k]q[l,v] (staged flush); tau[k] contiguous write
//  LAST: Z[l,v]=sum_k left[l,k]Y[k,v] (staged f32)
template<int LAST>
__global__ __launch_bounds__(256, 4) void da_kernel(
    const float* __restrict__ Q,
    const uint*  __restrict__ HmIn,   // [h][k][j][v] packed
    const float* __restrict__ alphaIn,// [h][k][j]
    const uint*  __restrict__ Yin,    // LAST only, packed
    uint*  __restrict__ Gout,         // !LAST, [h][j][k][v] packed
    float* __restrict__ tauOut,       // !LAST, [h][j][k]
    float* __restrict__ Zout)         // LAST
{
    __shared__ __align__(16) ushort SM[18432];
    ushort* Ah = SM;          ushort* Al = SM + 4608;   // q rows -> q^T / Y^T
    ushort* Bh = SM + 9216;   ushort* Bl = SM + 13824;  // Hm rows -> left
    uint*  OSB = (uint*)(SM + 9216);
    float* OSF = (float*)(SM + 9216);

    const int wg = swz_wg(blockIdx.x, 512), h = wg >> 6, j = wg & 63;
    const int tid = threadIdx.x, r = tid & 63, c0 = (tid >> 6) << 4;
    const int w = tid >> 6, lo4 = tid & 15, hi4 = (tid >> 4) & 3;

    // stage q (x0.125) -> A, keep regs for q^T
    Frag16 fq = split_load(Q + (size_t)h * HEADQ + (size_t)r * 4096 + (size_t)j * 64 + c0,
                           0.125f);
    store_rows(Ah, Al, r, c0, fq);
    { // stage Hm rows -> B (cheap unpack)
        store_rows(Bh, Bl, r, c0,
                   unpack_load(HmIn + ((size_t)h * 64 + r) * 4096 + (size_t)j * 64 + c0));
    }
    Frag16 fy;
    if (LAST)
        fy = unpack_load(Yin + ((size_t)h * 64 + r) * 4096 + (size_t)j * 64 + c0);
    // alpha[k] per in-lane k = 16m+4hi4+rg : [h][k][j] gather (L2-hot)
    float av[16];
    #pragma unroll
    for (int m = 0; m < 4; ++m)
        #pragma unroll
        for (int rg = 0; rg < 4; ++rg)
            av[4 * m + rg] = alphaIn[((size_t)h * 64 + 16 * m + 4 * hi4 + rg) * 64 + j];
    __syncthreads();

    // MM1 swapped: acc[m][rg] = beta2[k=16m+4hi4+rg][l=16w+lo4]
    f32x4 acc[4] = {};
    mmstep_swap(Ah, Al, Bh, Bl, w, lo4, hi4, acc);
    __syncthreads();

    // left = softmax over k: in-lane 16 + shfl_xor(16,32); per-lane l
    {
        const int l = 16 * w + lo4;
        float x[16];
        #pragma unroll
        for (int m = 0; m < 4; ++m)
            #pragma unroll
            for (int rg = 0; rg < 4; ++rg) x[4 * m + rg] = acc[m][rg] - av[4 * m + rg];
        float mx = max16(x);
        mx = fmaxf(mx, __shfl_xor(mx, 16));
        mx = fmaxf(mx, __shfl_xor(mx, 32));
        #pragma unroll
        for (int e = 0; e < 16; ++e) x[e] = __expf(x[e] - mx);
        float s = sum16(x);
        s += __shfl_xor(s, 16);
        s += __shfl_xor(s, 32);
        const float inv = 1.f / s;
        #pragma unroll
        for (int m = 0; m < 4; ++m) {
            #pragma unroll
            for (int rg = 0; rg < 4; ++rg) {
                const float lv = x[4 * m + rg] * inv;
                ushort hh, ll; bfsplit(lv, hh, ll);
                const int kk = 16 * m + 4 * hi4 + rg;
                if (!LAST) { Bh[kk * 72 + l] = hh; Bl[kk * 72 + l] = ll; }  // left^T [k][l]
                else       { Bh[l * 72 + kk] = hh; Bl[l * 72 + kk] = ll; }  // left [l][k]
            }
        }
    }
    if (!LAST) scatter_tr(Ah, Al, r, c0, fq);      // q^T over dead q rows
    else       scatter_tr(Ah, Al, r, c0, fy);      // Y^T over dead q rows
    __syncthreads();

    if (!LAST) {
        f32x4 acc2[4] = {};
        f32x4 tacc = {};
        short8v onesb;
        #pragma unroll
        for (int e2 = 0; e2 < 8; ++e2) onesb[e2] = (lo4 == 0) ? (short)0x3F80 : (short)0;
        #pragma unroll
        for (int ks = 0; ks < 2; ++ks) {
            short8v ah = LD8(Bh, 16 * w + lo4, hi4 + 4 * ks);   // left^T rows (k)
            short8v al = LD8(Bl, 16 * w + lo4, hi4 + 4 * ks);
            MFMA(tacc, ah, onesb); MFMA(tacc, al, onesb);
            #pragma unroll
            for (int t = 0; t < 4; ++t) {
                short8v bh = LD8(Ah, 16 * t + lo4, hi4 + 4 * ks); // q^T rows (v)
                short8v bl = LD8(Al, 16 * t + lo4, hi4 + 4 * ks);
                MFMA(acc2[t], ah, bh); MFMA(acc2[t], ah, bl); MFMA(acc2[t], al, bh);
            }
        }
        __syncthreads();
        #pragma unroll
        for (int rr = 0; rr < 4; ++rr) {           // stage G packed -> OSB; tau write
            const int kq = 16 * w + 4 * hi4 + rr;
            if (lo4 == 0) tauOut[((size_t)h * 64 + j) * 64 + kq] = tacc[rr];  // contig region
            #pragma unroll
            for (int t = 0; t < 4; ++t)
                OSB[kq * 68 + 16 * t + lo4] = packbf(acc2[t][rr]);
        }
        __syncthreads();
        flush_u32(OSB, Gout + ((size_t)h * 64 + j) * 4096, tid);
    } else {
        f32x4 acc2[4] = {};
        #pragma unroll
        for (int ks = 0; ks < 2; ++ks) {
            short8v ah = LD8(Bh, 16 * w + lo4, hi4 + 4 * ks);   // left rows (l)
            short8v al = LD8(Bl, 16 * w + lo4, hi4 + 4 * ks);
            #pragma unroll
            for (int t = 0; t < 4; ++t) {
                short8v bh = LD8(Ah, 16 * t + lo4, hi4 + 4 * ks); // Y^T rows (v)
                short8v bl = LD8(Al, 16 * t + lo4, hi4 + 4 * ks);
                MFMA(acc2[t], ah, bh); MFMA(acc2[t], ah, bl); MFMA(acc2[t], al, bh);
            }
        }
        __syncthreads();
        #pragma unroll
        for (int rr = 0; rr < 4; ++rr) {           // stage Z f32 -> OSF
            const int l = 16 * w + 4 * hi4 + rr;
            #pragma unroll
            for (int t = 0; t < 4; ++t) OSF[l * 68 + 16 * t + lo4] = acc2[t][rr];
        }
        __syncthreads();
        #pragma unroll
        for (int q = 0; q < 4; ++q) {              // 256-B chunk per 16-lane group
            const int l = (tid >> 4) + 16 * q;
            const int v4 = (tid & 15) * 4;
            float4 vv = *(const float4*)(OSF + l * 68 + v4);
            *(float4*)(Zout + (size_t)h * HEADQ + (size_t)l * 4096 + (size_t)j * 64 + v4) = vv;
        }
    }
}

} // namespace

extern "C" void kernel_launch(void* const* d_in, const int* in_sizes, int n_in,
                              void* d_out, int out_size, void* d_ws, size_t ws_size,
                              hipStream_t stream) {
    const float* Q = (const float*)d_in[0];
    const float* K = (const float*)d_in[1];
    const float* V = (const float*)d_in[2];
    float* out = (float*)d_out;

    char* ws = (char*)d_ws;
    const size_t MB = 1024 * 1024;
    uint*  G   = (uint*)(ws);                   // 64 MiB packed (fallback: z staging)
    uint*  Hm  = (uint*)(ws + 64 * MB);         // 64 MiB packed
    uint*  M   = (uint*)(ws + 128 * MB);        //  1 MiB packed
    float* al  = (float*)(ws + 129 * MB);       //  1 MiB
    float* tau = (float*)(ws + 130 * MB);       //  1 MiB

    const bool bigws = ws_size >= (size_t)195 * MB;
    uint*  Ybuf = bigws ? (uint*)(ws + 131 * MB) : (uint*)out;  // packed Y staging
    float* Zdst = bigws ? out : (float*)G;

    dim3 blk(256), grid(HEADS * 64);

    kmean_kernel<<<dim3(1024), blk, 0, stream>>>(Q, M);
    bc_kernel<1, 0><<<grid, blk, 0, stream>>>(M, K, nullptr, nullptr, Hm, al, nullptr);
    da_kernel<0>   <<<grid, blk, 0, stream>>>(Q, Hm, al, nullptr, G, tau, nullptr);
    bc_kernel<0, 0><<<grid, blk, 0, stream>>>(G, K, nullptr, tau, Hm, al, nullptr);
    da_kernel<0>   <<<grid, blk, 0, stream>>>(Q, Hm, al, nullptr, G, tau, nullptr);
    bc_kernel<0, 1><<<grid, blk, 0, stream>>>(G, K, V, tau, Hm, al, Ybuf);
    da_kernel<1>   <<<grid, blk, 0, stream>>>(Q, Hm, al, Ybuf, nullptr, nullptr, Zdst);
    if (!bigws)
        hipMemcpyAsync(d_out, Zdst, MATF * sizeof(float), hipMemcpyDeviceToDevice, stream);
}

// Round 11
// 305.433 us; speedup vs baseline: 1.0963x; 1.0963x over previous
//
#include <hip/hip_runtime.h>

// SOBA-Monarch, B*H=64 heads, S=4096, D=64, nb=bs=64, pad=0, 3 steps.
// Round 11 = R4 EXACTLY (f32 intermediates, split_load staging, pad-72 LDS,
// (256,4), grid 4096, LDS-staged output flushes) + the single isolated winner
// from R9: swapped-operand MM1 + in-lane softmax (2 shfls per reduce).
// Layouts: G [h][j][k][v] f32 | Hm,Y [h][k][j][v] f32 | M [h][j][v] f32
//          alpha [h][j][k] f32 (scatter write, contig read)
//          tau   [h][k][j] f32 (scatter write, contig read)

namespace {

typedef __attribute__((ext_vector_type(8))) short short8v;
typedef __attribute__((ext_vector_type(4))) float f32x4;

constexpr int HEADS = 64;
constexpr size_t HEADQ = 262144;                 // 4096*64 per head
constexpr size_t MATF  = (size_t)HEADS * 262144;

#define MFMA(ACC, A, B) ACC = __builtin_amdgcn_mfma_f32_16x16x32_bf16(A, B, ACC, 0, 0, 0)
#define LD8(arr, row, g8) (*(const short8v*)((arr) + (row) * 72 + (g8) * 8))

__device__ __forceinline__ void bfsplit(float x, ushort& h, ushort& l) {
    uint u = __float_as_uint(x);
    uint hi = (u + 0x7FFFu + ((u >> 16) & 1u)) & 0xFFFF0000u;
    h = (ushort)(hi >> 16);
    l = (ushort)(__float_as_uint(x - __uint_as_float(hi)) >> 16);
}

struct Frag16 { short8v h0, h1, l0, l1; };

// f32 global (16 elems) -> split regs
__device__ __forceinline__ Frag16 split_load(const float* __restrict__ p, float s) {
    Frag16 f;
    #pragma unroll
    for (int q = 0; q < 4; ++q) {
        float4 a = *(const float4*)(p + 4 * q);
        float v[4] = {a.x * s, a.y * s, a.z * s, a.w * s};
        #pragma unroll
        for (int e = 0; e < 4; ++e) {
            ushort hh, ll; bfsplit(v[e], hh, ll);
            const int i = 4 * q + e;
            if (i < 8) { f.h0[i] = (short)hh; f.l0[i] = (short)ll; }
            else       { f.h1[i - 8] = (short)hh; f.l1[i - 8] = (short)ll; }
        }
    }
    return f;
}
__device__ __forceinline__ void store_rows(ushort* H, ushort* L, int r, int c0,
                                           const Frag16& f) {
    *(short8v*)(H + r * 72 + c0)     = f.h0;
    *(short8v*)(H + r * 72 + c0 + 8) = f.h1;
    *(short8v*)(L + r * 72 + c0)     = f.l0;
    *(short8v*)(L + r * 72 + c0 + 8) = f.l1;
}
__device__ __forceinline__ void scatter_tr(ushort* H, ushort* L, int r, int c0,
                                           const Frag16& f) {
    #pragma unroll
    for (int e = 0; e < 8; ++e) {
        H[(c0 + e) * 72 + r] = (ushort)f.h0[e];
        L[(c0 + e) * 72 + r] = (ushort)f.l0[e];
    }
    #pragma unroll
    for (int e = 0; e < 8; ++e) {
        H[(c0 + 8 + e) * 72 + r] = (ushort)f.h1[e];
        L[(c0 + 8 + e) * 72 + r] = (ushort)f.l1[e];
    }
}

// staged [64][68] f32 tile -> contiguous 16KB global block
__device__ __forceinline__ void flush_f32(const float* OS, float* g, int tid) {
    #pragma unroll
    for (int q = 0; q < 4; ++q) {
        const int off = tid * 4 + q * 1024;
        float4 v = *(const float4*)(OS + (off >> 6) * 68 + (off & 63));
        *(float4*)(g + off) = v;
    }
}

__device__ __forceinline__ void mmstep(const ushort* AH, const ushort* AL,
                                       const ushort* BH, const ushort* BL,
                                       int w, int lo4, int hi4, f32x4 acc[4]) {
    #pragma unroll
    for (int ks = 0; ks < 2; ++ks) {
        short8v ah = LD8(AH, 16 * w + lo4, hi4 + 4 * ks);
        short8v al = LD8(AL, 16 * w + lo4, hi4 + 4 * ks);
        #pragma unroll
        for (int t = 0; t < 4; ++t) {
            short8v bh = LD8(BH, 16 * t + lo4, hi4 + 4 * ks);
            short8v bl = LD8(BL, 16 * t + lo4, hi4 + 4 * ks);
            MFMA(acc[t], ah, bh); MFMA(acc[t], ah, bl); MFMA(acc[t], al, bh);
        }
    }
}
// swapped: acc[m] = A-strip m (from B region) x B-strip w (from A region)
__device__ __forceinline__ void mmstep_swap(const ushort* AH, const ushort* AL,
                                            const ushort* BH, const ushort* BL,
                                            int w, int lo4, int hi4, f32x4 acc[4]) {
    #pragma unroll
    for (int ks = 0; ks < 2; ++ks) {
        short8v bh = LD8(AH, 16 * w + lo4, hi4 + 4 * ks);
        short8v bl = LD8(AL, 16 * w + lo4, hi4 + 4 * ks);
        #pragma unroll
        for (int m = 0; m < 4; ++m) {
            short8v ah = LD8(BH, 16 * m + lo4, hi4 + 4 * ks);
            short8v al = LD8(BL, 16 * m + lo4, hi4 + 4 * ks);
            MFMA(acc[m], ah, bh); MFMA(acc[m], ah, bl); MFMA(acc[m], al, bh);
        }
    }
}

__device__ __forceinline__ float max16(const float* x) {
    float a = fmaxf(fmaxf(x[0], x[1]), fmaxf(x[2], x[3]));
    float b = fmaxf(fmaxf(x[4], x[5]), fmaxf(x[6], x[7]));
    float c = fmaxf(fmaxf(x[8], x[9]), fmaxf(x[10], x[11]));
    float d = fmaxf(fmaxf(x[12], x[13]), fmaxf(x[14], x[15]));
    return fmaxf(fmaxf(a, b), fmaxf(c, d));
}
__device__ __forceinline__ float sum16(const float* x) {
    float a = (x[0] + x[1]) + (x[2] + x[3]);
    float b = (x[4] + x[5]) + (x[6] + x[7]);
    float c = (x[8] + x[9]) + (x[10] + x[11]);
    float d = (x[12] + x[13]) + (x[14] + x[15]);
    return (a + b) + (c + d);
}

// M[h][j][v] = (1/512) * sum_l Q[h][l*64+j][v]
__global__ __launch_bounds__(256) void kmean_kernel(const float* __restrict__ Q,
                                                    float* __restrict__ M) {
    const int wg = blockIdx.x;                      // 1024 WGs
    const int h  = wg >> 4;
    const int j  = ((wg & 15) << 2) + (threadIdx.x >> 6);
    const int v  = threadIdx.x & 63;
    const float* base = Q + (size_t)h * HEADQ + (size_t)j * 64 + v;
    float acc = 0.f;
    #pragma unroll
    for (int l = 0; l < 64; ++l) acc += base[(size_t)l * 4096];
    M[((size_t)h * 64 + j) * 64 + v] = acc * (1.0f / 512.0f);
}

// One WG (256T) per (h,k).
// MM1 (swapped): beta^T[i,j]; in-lane softmax over i; alpha[j]=sum r log r
// MM2: Hm[j,v]=sum_i right[j,i]K[i,v];  LAST: Y[j,v]=sum_i right[j,i]V[i,v]
template<int FIRST, int LAST>
__global__ __launch_bounds__(256, 4) void bc_kernel(
    const float* __restrict__ Gsrc,   // FIRST ? M[h][j][v] : G[h][j][k][v]
    const float* __restrict__ Kmat,
    const float* __restrict__ Vmat,   // LAST only
    const float* __restrict__ tauIn,  // !FIRST, [h][k][j]
    float* __restrict__ HmOut,        // [h][k][j][v]
    float* __restrict__ alphaOut,     // [h][j][k]
    float* __restrict__ Yout)         // LAST only, [h][k][j][v]
{
    __shared__ __align__(16) ushort SM[18432];     // 36864 B -> 4 WG/CU
    ushort* Ah = SM;          ushort* Al = SM + 4608;   // G rows -> right rows
    ushort* Bh = SM + 9216;   ushort* Bl = SM + 13824;  // K rows -> K^T -> V^T
    float* OSA = (float*)SM;                            // staging over A (18432 B)
    float* OSB = (float*)(SM + 9216);                   // staging over B

    const int wg = blockIdx.x, h = wg >> 6, k = wg & 63;
    const int tid = threadIdx.x, r = tid & 63, c0 = (tid >> 6) << 4;
    const int w = tid >> 6, lo4 = tid & 15, hi4 = (tid >> 4) & 3;

    { // stage G rows -> A
        const float* gp = FIRST ? Gsrc + ((size_t)h * 64 + r) * 64 + c0
                                : Gsrc + ((size_t)h * 64 + r) * 4096 + (size_t)k * 64 + c0;
        store_rows(Ah, Al, r, c0, split_load(gp, 1.f));
    }
    // stage K rows -> B, keep regs for K^T scatter
    Frag16 fk = split_load(Kmat + (size_t)h * HEADQ + (size_t)k * 4096 + r * 64 + c0, 1.f);
    store_rows(Bh, Bl, r, c0, fk);
    Frag16 fv;
    if (LAST)
        fv = split_load(Vmat + (size_t)h * HEADQ + (size_t)k * 4096 + r * 64 + c0, 1.f);
    // tau: one scalar per lane (j = 16w + lo4), [h][k][j] contiguous read
    float tv = 1.f;
    if (!FIRST) tv = tauIn[((size_t)h * 64 + k) * 64 + 16 * w + lo4];
    __syncthreads();

    // MM1 swapped: acc[m][reg] = beta[i=16m+4hi4+reg][j=16w+lo4]
    f32x4 acc[4] = {};
    mmstep_swap(Ah, Al, Bh, Bl, w, lo4, hi4, acc);
    __syncthreads();

    // softmax over i: in-lane 16 + shfl_xor(16,32); per-lane j
    {
        const int j = 16 * w + lo4;
        const bool tz = !(tv > 1e-8f);
        const float tvi = tz ? 1.f : 1.f / tv;
        float x[16];
        #pragma unroll
        for (int m = 0; m < 4; ++m)
            #pragma unroll
            for (int rg = 0; rg < 4; ++rg) x[4 * m + rg] = acc[m][rg] * tvi;
        float mx = max16(x);
        mx = fmaxf(mx, __shfl_xor(mx, 16));
        mx = fmaxf(mx, __shfl_xor(mx, 32));
        #pragma unroll
        for (int e = 0; e < 16; ++e) x[e] = __expf(x[e] - mx);
        float s = sum16(x);
        s += __shfl_xor(s, 16);
        s += __shfl_xor(s, 32);
        const float inv = 1.f / s;
        float ap = 0.f;
        #pragma unroll
        for (int m = 0; m < 4; ++m) {
            #pragma unroll
            for (int rg = 0; rg < 4; ++rg) {
                const float rv = tz ? (1.f / 64.f) : x[4 * m + rg] * inv;
                ap += (rv > 0.f) ? rv * __logf(rv) : 0.f;
                ushort hh, ll; bfsplit(rv, hh, ll);
                const int i = 16 * m + 4 * hi4 + rg;
                Ah[j * 72 + i] = hh;                 // right rows [j][i]
                Al[j * 72 + i] = ll;
            }
        }
        ap += __shfl_xor(ap, 16);
        ap += __shfl_xor(ap, 32);
        if (hi4 == 0) alphaOut[((size_t)h * 64 + j) * 64 + k] = ap;
    }
    scatter_tr(Bh, Bl, r, c0, fk);                 // K^T over dead K rows
    __syncthreads();

    f32x4 acc2[4] = {};
    mmstep(Ah, Al, Bh, Bl, w, lo4, hi4, acc2);     // Hm: A=right rows, B=K^T
    const size_t ob = ((size_t)h * 64 + k) * 4096;
    if (!LAST) {
        __syncthreads();
        #pragma unroll
        for (int rr = 0; rr < 4; ++rr) {           // stage Hm f32 -> OSB
            const int j = 16 * w + 4 * hi4 + rr;
            #pragma unroll
            for (int t = 0; t < 4; ++t)
                OSB[j * 68 + 16 * t + lo4] = acc2[t][rr];
        }
        __syncthreads();
        flush_f32(OSB, HmOut + ob, tid);
    } else {
        __syncthreads();
        scatter_tr(Bh, Bl, r, c0, fv);             // V^T over dead K^T
        __syncthreads();
        f32x4 acc3[4] = {};
        mmstep(Ah, Al, Bh, Bl, w, lo4, hi4, acc3); // Y: A=right, B=V^T
        __syncthreads();
        #pragma unroll
        for (int rr = 0; rr < 4; ++rr) {           // stage Hm -> OSA, Y -> OSB
            const int j = 16 * w + 4 * hi4 + rr;
            #pragma unroll
            for (int t = 0; t < 4; ++t) {
                OSA[j * 68 + 16 * t + lo4] = acc2[t][rr];
                OSB[j * 68 + 16 * t + lo4] = acc3[t][rr];
            }
        }
        __syncthreads();
        flush_f32(OSA, HmOut + ob, tid);
        flush_f32(OSB, Yout + ob, tid);
    }
}

// One WG per (h,j).
// MM1 (swapped): beta2^T[k,l]; in-lane softmax over k
// !LAST: G[k,v]=sum_l left[l,k]q[l,v] (staged flush); tau[k] via ones-MFMA
//  LAST: Z[l,v]=sum_k left[l,k]Y[k,v] (staged f32)
template<int LAST>
__global__ __launch_bounds__(256, 4) void da_kernel(
    const float* __restrict__ Q,
    const float* __restrict__ HmIn,   // [h][k][j][v]
    const float* __restrict__ alphaIn,// [h][j][k]
    const float* __restrict__ Yin,    // LAST only
    float* __restrict__ Gout,         // !LAST, [h][j][k][v]
    float* __restrict__ tauOut,       // !LAST, [h][k][j]
    float* __restrict__ Zout)         // LAST
{
    __shared__ __align__(16) ushort SM[18432];
    ushort* Ah = SM;          ushort* Al = SM + 4608;   // q rows -> q^T / Y^T
    ushort* Bh = SM + 9216;   ushort* Bl = SM + 13824;  // Hm rows -> left
    float* OSB = (float*)(SM + 9216);

    const int wg = blockIdx.x, h = wg >> 6, j = wg & 63;
    const int tid = threadIdx.x, r = tid & 63, c0 = (tid >> 6) << 4;
    const int w = tid >> 6, lo4 = tid & 15, hi4 = (tid >> 4) & 3;

    // stage q (x0.125) -> A, keep regs for q^T
    Frag16 fq = split_load(Q + (size_t)h * HEADQ + (size_t)r * 4096 + (size_t)j * 64 + c0,
                           0.125f);
    store_rows(Ah, Al, r, c0, fq);
    { // stage Hm rows -> B
        store_rows(Bh, Bl, r, c0,
                   split_load(HmIn + ((size_t)h * 64 + r) * 4096 + (size_t)j * 64 + c0, 1.f));
    }
    Frag16 fy;
    if (LAST)
        fy = split_load(Yin + ((size_t)h * 64 + r) * 4096 + (size_t)j * 64 + c0, 1.f);
    // alpha[k] per in-lane k = 16m+4hi4+rg : [h][j][k] contiguous 256-B row
    float av[16];
    {
        const float* ap0 = alphaIn + ((size_t)h * 64 + j) * 64 + 4 * hi4;
        #pragma unroll
        for (int m = 0; m < 4; ++m)
            #pragma unroll
            for (int rg = 0; rg < 4; ++rg) av[4 * m + rg] = ap0[16 * m + rg];
    }
    __syncthreads();

    // MM1 swapped: acc[m][rg] = beta2[k=16m+4hi4+rg][l=16w+lo4]
    f32x4 acc[4] = {};
    mmstep_swap(Ah, Al, Bh, Bl, w, lo4, hi4, acc);
    __syncthreads();

    // left = softmax over k: in-lane 16 + shfl_xor(16,32); per-lane l
    {
        const int l = 16 * w + lo4;
        float x[16];
        #pragma unroll
        for (int m = 0; m < 4; ++m)
            #pragma unroll
            for (int rg = 0; rg < 4; ++rg) x[4 * m + rg] = acc[m][rg] - av[4 * m + rg];
        float mx = max16(x);
        mx = fmaxf(mx, __shfl_xor(mx, 16));
        mx = fmaxf(mx, __shfl_xor(mx, 32));
        #pragma unroll
        for (int e = 0; e < 16; ++e) x[e] = __expf(x[e] - mx);
        float s = sum16(x);
        s += __shfl_xor(s, 16);
        s += __shfl_xor(s, 32);
        const float inv = 1.f / s;
        #pragma unroll
        for (int m = 0; m < 4; ++m) {
            #pragma unroll
            for (int rg = 0; rg < 4; ++rg) {
                const float lv = x[4 * m + rg] * inv;
                ushort hh, ll; bfsplit(lv, hh, ll);
                const int kk = 16 * m + 4 * hi4 + rg;
                if (!LAST) { Bh[kk * 72 + l] = hh; Bl[kk * 72 + l] = ll; }  // left^T [k][l]
                else       { Bh[l * 72 + kk] = hh; Bl[l * 72 + kk] = ll; }  // left [l][k]
            }
        }
    }
    if (!LAST) scatter_tr(Ah, Al, r, c0, fq);      // q^T over dead q rows
    else       scatter_tr(Ah, Al, r, c0, fy);      // Y^T over dead q rows
    __syncthreads();

    if (!LAST) {
        f32x4 acc2[4] = {};
        f32x4 tacc = {};
        short8v onesb;
        #pragma unroll
        for (int e2 = 0; e2 < 8; ++e2) onesb[e2] = (lo4 == 0) ? (short)0x3F80 : (short)0;
        #pragma unroll
        for (int ks = 0; ks < 2; ++ks) {
            short8v ah = LD8(Bh, 16 * w + lo4, hi4 + 4 * ks);   // left^T rows (k)
            short8v al = LD8(Bl, 16 * w + lo4, hi4 + 4 * ks);
            MFMA(tacc, ah, onesb); MFMA(tacc, al, onesb);
            #pragma unroll
            for (int t = 0; t < 4; ++t) {
                short8v bh = LD8(Ah, 16 * t + lo4, hi4 + 4 * ks); // q^T rows (v)
                short8v bl = LD8(Al, 16 * t + lo4, hi4 + 4 * ks);
                MFMA(acc2[t], ah, bh); MFMA(acc2[t], ah, bl); MFMA(acc2[t], al, bh);
            }
        }
        __syncthreads();
        #pragma unroll
        for (int rr = 0; rr < 4; ++rr) {           // stage G f32 -> OSB; tau scatter
            const int kq = 16 * w + 4 * hi4 + rr;
            if (lo4 == 0) tauOut[((size_t)h * 64 + kq) * 64 + j] = tacc[rr];
            #pragma unroll
            for (int t = 0; t < 4; ++t)
                OSB[kq * 68 + 16 * t + lo4] = acc2[t][rr];
        }
        __syncthreads();
        flush_f32(OSB, Gout + ((size_t)h * 64 + j) * 4096, tid);
    } else {
        f32x4 acc2[4] = {};
        #pragma unroll
        for (int ks = 0; ks < 2; ++ks) {
            short8v ah = LD8(Bh, 16 * w + lo4, hi4 + 4 * ks);   // left rows (l)
            short8v al = LD8(Bl, 16 * w + lo4, hi4 + 4 * ks);
            #pragma unroll
            for (int t = 0; t < 4; ++t) {
                short8v bh = LD8(Ah, 16 * t + lo4, hi4 + 4 * ks); // Y^T rows (v)
                short8v bl = LD8(Al, 16 * t + lo4, hi4 + 4 * ks);
                MFMA(acc2[t], ah, bh); MFMA(acc2[t], ah, bl); MFMA(acc2[t], al, bh);
            }
        }
        __syncthreads();
        #pragma unroll
        for (int rr = 0; rr < 4; ++rr) {           // stage Z f32 -> OSB
            const int l = 16 * w + 4 * hi4 + rr;
            #pragma unroll
            for (int t = 0; t < 4; ++t) OSB[l * 68 + 16 * t + lo4] = acc2[t][rr];
        }
        __syncthreads();
        #pragma unroll
        for (int q = 0; q < 4; ++q) {              // 256-B chunk per 16-lane group
            const int l = (tid >> 4) + 16 * q;
            const int v4 = (tid & 15) * 4;
            float4 vv = *(const float4*)(OSB + l * 68 + v4);
            *(float4*)(Zout + (size_t)h * HEADQ + (size_t)l * 4096 + (size_t)j * 64 + v4) = vv;
        }
    }
}

} // namespace

extern "C" void kernel_launch(void* const* d_in, const int* in_sizes, int n_in,
                              void* d_out, int out_size, void* d_ws, size_t ws_size,
                              hipStream_t stream) {
    const float* Q = (const float*)d_in[0];
    const float* K = (const float*)d_in[1];
    const float* V = (const float*)d_in[2];
    float* out = (float*)d_out;

    char* ws = (char*)d_ws;
    const size_t MB = 1024 * 1024;
    float* G   = (float*)(ws);                  // 64 MiB (fallback: z staging)
    float* Hm  = (float*)(ws + 64 * MB);        // 64 MiB
    float* M   = (float*)(ws + 128 * MB);       //  1 MiB
    float* al  = (float*)(ws + 129 * MB);       //  1 MiB
    float* tau = (float*)(ws + 130 * MB);       //  1 MiB

    const bool bigws = ws_size >= (size_t)195 * MB;
    float* Ybuf = bigws ? (float*)(ws + 131 * MB) : out;   // Y staging
    float* Zdst = bigws ? out : G;

    dim3 blk(256), grid(HEADS * 64);

    kmean_kernel<<<dim3(1024), blk, 0, stream>>>(Q, M);
    bc_kernel<1, 0><<<grid, blk, 0, stream>>>(M, K, nullptr, nullptr, Hm, al, nullptr);
    da_kernel<0>   <<<grid, blk, 0, stream>>>(Q, Hm, al, nullptr, G, tau, nullptr);
    bc_kernel<0, 0><<<grid, blk, 0, stream>>>(G, K, nullptr, tau, Hm, al, nullptr);
    da_kernel<0>   <<<grid, blk, 0, stream>>>(Q, Hm, al, nullptr, G, tau, nullptr);
    bc_kernel<0, 1><<<grid, blk, 0, stream>>>(G, K, V, tau, Hm, al, Ybuf);
    da_kernel<1>   <<<grid, blk, 0, stream>>>(Q, Hm, al, Ybuf, nullptr, nullptr, Zdst);
    if (!bigws)
        hipMemcpyAsync(d_out, Zdst, MATF * sizeof(float), hipMemcpyDeviceToDevice, stream);
}

// Round 12
// 302.282 us; speedup vs baseline: 1.1078x; 1.0104x over previous
//
#include <hip/hip_runtime.h>

// SOBA-Monarch, B*H=64 heads, S=4096, D=64, nb=bs=64, pad=0, 3 steps.
// Round 12 = R11 + ONE change: alpha via entropy identity
//   sum r log r = P/S - mx - log S   (P = sum e_i x_i, fused fma)
//   -> 1 logf per lane instead of 16 (bc softmax critical path).
// Layouts: G [h][j][k][v] f32 | Hm,Y [h][k][j][v] f32 | M [h][j][v] f32
//          alpha [h][j][k] f32 (scatter write, contig read)
//          tau   [h][k][j] f32 (scatter write, contig read)

namespace {

typedef __attribute__((ext_vector_type(8))) short short8v;
typedef __attribute__((ext_vector_type(4))) float f32x4;

constexpr int HEADS = 64;
constexpr size_t HEADQ = 262144;                 // 4096*64 per head
constexpr size_t MATF  = (size_t)HEADS * 262144;

#define MFMA(ACC, A, B) ACC = __builtin_amdgcn_mfma_f32_16x16x32_bf16(A, B, ACC, 0, 0, 0)
#define LD8(arr, row, g8) (*(const short8v*)((arr) + (row) * 72 + (g8) * 8))

__device__ __forceinline__ void bfsplit(float x, ushort& h, ushort& l) {
    uint u = __float_as_uint(x);
    uint hi = (u + 0x7FFFu + ((u >> 16) & 1u)) & 0xFFFF0000u;
    h = (ushort)(hi >> 16);
    l = (ushort)(__float_as_uint(x - __uint_as_float(hi)) >> 16);
}

struct Frag16 { short8v h0, h1, l0, l1; };

// f32 global (16 elems) -> split regs
__device__ __forceinline__ Frag16 split_load(const float* __restrict__ p, float s) {
    Frag16 f;
    #pragma unroll
    for (int q = 0; q < 4; ++q) {
        float4 a = *(const float4*)(p + 4 * q);
        float v[4] = {a.x * s, a.y * s, a.z * s, a.w * s};
        #pragma unroll
        for (int e = 0; e < 4; ++e) {
            ushort hh, ll; bfsplit(v[e], hh, ll);
            const int i = 4 * q + e;
            if (i < 8) { f.h0[i] = (short)hh; f.l0[i] = (short)ll; }
            else       { f.h1[i - 8] = (short)hh; f.l1[i - 8] = (short)ll; }
        }
    }
    return f;
}
__device__ __forceinline__ void store_rows(ushort* H, ushort* L, int r, int c0,
                                           const Frag16& f) {
    *(short8v*)(H + r * 72 + c0)     = f.h0;
    *(short8v*)(H + r * 72 + c0 + 8) = f.h1;
    *(short8v*)(L + r * 72 + c0)     = f.l0;
    *(short8v*)(L + r * 72 + c0 + 8) = f.l1;
}
__device__ __forceinline__ void scatter_tr(ushort* H, ushort* L, int r, int c0,
                                           const Frag16& f) {
    #pragma unroll
    for (int e = 0; e < 8; ++e) {
        H[(c0 + e) * 72 + r] = (ushort)f.h0[e];
        L[(c0 + e) * 72 + r] = (ushort)f.l0[e];
    }
    #pragma unroll
    for (int e = 0; e < 8; ++e) {
        H[(c0 + 8 + e) * 72 + r] = (ushort)f.h1[e];
        L[(c0 + 8 + e) * 72 + r] = (ushort)f.l1[e];
    }
}

// staged [64][68] f32 tile -> contiguous 16KB global block
__device__ __forceinline__ void flush_f32(const float* OS, float* g, int tid) {
    #pragma unroll
    for (int q = 0; q < 4; ++q) {
        const int off = tid * 4 + q * 1024;
        float4 v = *(const float4*)(OS + (off >> 6) * 68 + (off & 63));
        *(float4*)(g + off) = v;
    }
}

__device__ __forceinline__ void mmstep(const ushort* AH, const ushort* AL,
                                       const ushort* BH, const ushort* BL,
                                       int w, int lo4, int hi4, f32x4 acc[4]) {
    #pragma unroll
    for (int ks = 0; ks < 2; ++ks) {
        short8v ah = LD8(AH, 16 * w + lo4, hi4 + 4 * ks);
        short8v al = LD8(AL, 16 * w + lo4, hi4 + 4 * ks);
        #pragma unroll
        for (int t = 0; t < 4; ++t) {
            short8v bh = LD8(BH, 16 * t + lo4, hi4 + 4 * ks);
            short8v bl = LD8(BL, 16 * t + lo4, hi4 + 4 * ks);
            MFMA(acc[t], ah, bh); MFMA(acc[t], ah, bl); MFMA(acc[t], al, bh);
        }
    }
}
// swapped: acc[m] = A-strip m (from B region) x B-strip w (from A region)
__device__ __forceinline__ void mmstep_swap(const ushort* AH, const ushort* AL,
                                            const ushort* BH, const ushort* BL,
                                            int w, int lo4, int hi4, f32x4 acc[4]) {
    #pragma unroll
    for (int ks = 0; ks < 2; ++ks) {
        short8v bh = LD8(AH, 16 * w + lo4, hi4 + 4 * ks);
        short8v bl = LD8(AL, 16 * w + lo4, hi4 + 4 * ks);
        #pragma unroll
        for (int m = 0; m < 4; ++m) {
            short8v ah = LD8(BH, 16 * m + lo4, hi4 + 4 * ks);
            short8v al = LD8(BL, 16 * m + lo4, hi4 + 4 * ks);
            MFMA(acc[m], ah, bh); MFMA(acc[m], ah, bl); MFMA(acc[m], al, bh);
        }
    }
}

__device__ __forceinline__ float max16(const float* x) {
    float a = fmaxf(fmaxf(x[0], x[1]), fmaxf(x[2], x[3]));
    float b = fmaxf(fmaxf(x[4], x[5]), fmaxf(x[6], x[7]));
    float c = fmaxf(fmaxf(x[8], x[9]), fmaxf(x[10], x[11]));
    float d = fmaxf(fmaxf(x[12], x[13]), fmaxf(x[14], x[15]));
    return fmaxf(fmaxf(a, b), fmaxf(c, d));
}

// M[h][j][v] = (1/512) * sum_l Q[h][l*64+j][v]
__global__ __launch_bounds__(256) void kmean_kernel(const float* __restrict__ Q,
                                                    float* __restrict__ M) {
    const int wg = blockIdx.x;                      // 1024 WGs
    const int h  = wg >> 4;
    const int j  = ((wg & 15) << 2) + (threadIdx.x >> 6);
    const int v  = threadIdx.x & 63;
    const float* base = Q + (size_t)h * HEADQ + (size_t)j * 64 + v;
    float acc = 0.f;
    #pragma unroll
    for (int l = 0; l < 64; ++l) acc += base[(size_t)l * 4096];
    M[((size_t)h * 64 + j) * 64 + v] = acc * (1.0f / 512.0f);
}

// One WG (256T) per (h,k).
// MM1 (swapped): beta^T[i,j]; in-lane softmax over i; alpha via entropy identity
// MM2: Hm[j,v]=sum_i right[j,i]K[i,v];  LAST: Y[j,v]=sum_i right[j,i]V[i,v]
template<int FIRST, int LAST>
__global__ __launch_bounds__(256, 4) void bc_kernel(
    const float* __restrict__ Gsrc,   // FIRST ? M[h][j][v] : G[h][j][k][v]
    const float* __restrict__ Kmat,
    const float* __restrict__ Vmat,   // LAST only
    const float* __restrict__ tauIn,  // !FIRST, [h][k][j]
    float* __restrict__ HmOut,        // [h][k][j][v]
    float* __restrict__ alphaOut,     // [h][j][k]
    float* __restrict__ Yout)         // LAST only, [h][k][j][v]
{
    __shared__ __align__(16) ushort SM[18432];     // 36864 B -> 4 WG/CU
    ushort* Ah = SM;          ushort* Al = SM + 4608;   // G rows -> right rows
    ushort* Bh = SM + 9216;   ushort* Bl = SM + 13824;  // K rows -> K^T -> V^T
    float* OSA = (float*)SM;                            // staging over A
    float* OSB = (float*)(SM + 9216);                   // staging over B

    const int wg = blockIdx.x, h = wg >> 6, k = wg & 63;
    const int tid = threadIdx.x, r = tid & 63, c0 = (tid >> 6) << 4;
    const int w = tid >> 6, lo4 = tid & 15, hi4 = (tid >> 4) & 3;

    { // stage G rows -> A
        const float* gp = FIRST ? Gsrc + ((size_t)h * 64 + r) * 64 + c0
                                : Gsrc + ((size_t)h * 64 + r) * 4096 + (size_t)k * 64 + c0;
        store_rows(Ah, Al, r, c0, split_load(gp, 1.f));
    }
    // stage K rows -> B, keep regs for K^T scatter
    Frag16 fk = split_load(Kmat + (size_t)h * HEADQ + (size_t)k * 4096 + r * 64 + c0, 1.f);
    store_rows(Bh, Bl, r, c0, fk);
    Frag16 fv;
    if (LAST)
        fv = split_load(Vmat + (size_t)h * HEADQ + (size_t)k * 4096 + r * 64 + c0, 1.f);
    // tau: one scalar per lane (j = 16w + lo4), [h][k][j] contiguous read
    float tv = 1.f;
    if (!FIRST) tv = tauIn[((size_t)h * 64 + k) * 64 + 16 * w + lo4];
    __syncthreads();

    // MM1 swapped: acc[m][reg] = beta[i=16m+4hi4+reg][j=16w+lo4]
    f32x4 acc[4] = {};
    mmstep_swap(Ah, Al, Bh, Bl, w, lo4, hi4, acc);
    __syncthreads();

    // softmax over i: in-lane 16 + shfl_xor(16,32); per-lane j
    // alpha = sum r log r = P/S - mx - log(S)   (P = sum e_i * x_i)
    {
        const int j = 16 * w + lo4;
        const bool tz = !(tv > 1e-8f);
        const float tvi = tz ? 1.f : 1.f / tv;
        float x[16];
        #pragma unroll
        for (int m = 0; m < 4; ++m)
            #pragma unroll
            for (int rg = 0; rg < 4; ++rg) x[4 * m + rg] = acc[m][rg] * tvi;
        float mx = max16(x);
        mx = fmaxf(mx, __shfl_xor(mx, 16));
        mx = fmaxf(mx, __shfl_xor(mx, 32));
        float ex[16], s = 0.f, p = 0.f;
        #pragma unroll
        for (int e = 0; e < 16; ++e) {
            ex[e] = __expf(x[e] - mx);
            s += ex[e];
            p = fmaf(ex[e], x[e], p);
        }
        s += __shfl_xor(s, 16);
        s += __shfl_xor(s, 32);
        p += __shfl_xor(p, 16);
        p += __shfl_xor(p, 32);
        const float inv = 1.f / s;
        const float ap = tz ? -4.1588830834f            // -log(64)
                            : fmaf(p, inv, -mx - __logf(s));
        #pragma unroll
        for (int m = 0; m < 4; ++m) {
            #pragma unroll
            for (int rg = 0; rg < 4; ++rg) {
                const float rv = tz ? (1.f / 64.f) : ex[4 * m + rg] * inv;
                ushort hh, ll; bfsplit(rv, hh, ll);
                const int i = 16 * m + 4 * hi4 + rg;
                Ah[j * 72 + i] = hh;                 // right rows [j][i]
                Al[j * 72 + i] = ll;
            }
        }
        if (hi4 == 0) alphaOut[((size_t)h * 64 + j) * 64 + k] = ap;
    }
    scatter_tr(Bh, Bl, r, c0, fk);                 // K^T over dead K rows
    __syncthreads();

    f32x4 acc2[4] = {};
    mmstep(Ah, Al, Bh, Bl, w, lo4, hi4, acc2);     // Hm: A=right rows, B=K^T
    const size_t ob = ((size_t)h * 64 + k) * 4096;
    if (!LAST) {
        __syncthreads();
        #pragma unroll
        for (int rr = 0; rr < 4; ++rr) {           // stage Hm f32 -> OSB
            const int j = 16 * w + 4 * hi4 + rr;
            #pragma unroll
            for (int t = 0; t < 4; ++t)
                OSB[j * 68 + 16 * t + lo4] = acc2[t][rr];
        }
        __syncthreads();
        flush_f32(OSB, HmOut + ob, tid);
    } else {
        __syncthreads();
        scatter_tr(Bh, Bl, r, c0, fv);             // V^T over dead K^T
        __syncthreads();
        f32x4 acc3[4] = {};
        mmstep(Ah, Al, Bh, Bl, w, lo4, hi4, acc3); // Y: A=right, B=V^T
        __syncthreads();
        #pragma unroll
        for (int rr = 0; rr < 4; ++rr) {           // stage Hm -> OSA, Y -> OSB
            const int j = 16 * w + 4 * hi4 + rr;
            #pragma unroll
            for (int t = 0; t < 4; ++t) {
                OSA[j * 68 + 16 * t + lo4] = acc2[t][rr];
                OSB[j * 68 + 16 * t + lo4] = acc3[t][rr];
            }
        }
        __syncthreads();
        flush_f32(OSA, HmOut + ob, tid);
        flush_f32(OSB, Yout + ob, tid);
    }
}

// One WG per (h,j).
// MM1 (swapped): beta2^T[k,l]; in-lane softmax over k
// !LAST: G[k,v]=sum_l left[l,k]q[l,v] (staged flush); tau[k] via ones-MFMA
//  LAST: Z[l,v]=sum_k left[l,k]Y[k,v] (staged f32)
template<int LAST>
__global__ __launch_bounds__(256, 4) void da_kernel(
    const float* __restrict__ Q,
    const float* __restrict__ HmIn,   // [h][k][j][v]
    const float* __restrict__ alphaIn,// [h][j][k]
    const float* __restrict__ Yin,    // LAST only
    float* __restrict__ Gout,         // !LAST, [h][j][k][v]
    float* __restrict__ tauOut,       // !LAST, [h][k][j]
    float* __restrict__ Zout)         // LAST
{
    __shared__ __align__(16) ushort SM[18432];
    ushort* Ah = SM;          ushort* Al = SM + 4608;   // q rows -> q^T / Y^T
    ushort* Bh = SM + 9216;   ushort* Bl = SM + 13824;  // Hm rows -> left
    float* OSB = (float*)(SM + 9216);

    const int wg = blockIdx.x, h = wg >> 6, j = wg & 63;
    const int tid = threadIdx.x, r = tid & 63, c0 = (tid >> 6) << 4;
    const int w = tid >> 6, lo4 = tid & 15, hi4 = (tid >> 4) & 3;

    // stage q (x0.125) -> A, keep regs for q^T
    Frag16 fq = split_load(Q + (size_t)h * HEADQ + (size_t)r * 4096 + (size_t)j * 64 + c0,
                           0.125f);
    store_rows(Ah, Al, r, c0, fq);
    { // stage Hm rows -> B
        store_rows(Bh, Bl, r, c0,
                   split_load(HmIn + ((size_t)h * 64 + r) * 4096 + (size_t)j * 64 + c0, 1.f));
    }
    Frag16 fy;
    if (LAST)
        fy = split_load(Yin + ((size_t)h * 64 + r) * 4096 + (size_t)j * 64 + c0, 1.f);
    // alpha[k] per in-lane k = 16m+4hi4+rg : [h][j][k] contiguous 256-B row
    float av[16];
    {
        const float* ap0 = alphaIn + ((size_t)h * 64 + j) * 64 + 4 * hi4;
        #pragma unroll
        for (int m = 0; m < 4; ++m)
            #pragma unroll
            for (int rg = 0; rg < 4; ++rg) av[4 * m + rg] = ap0[16 * m + rg];
    }
    __syncthreads();

    // MM1 swapped: acc[m][rg] = beta2[k=16m+4hi4+rg][l=16w+lo4]
    f32x4 acc[4] = {};
    mmstep_swap(Ah, Al, Bh, Bl, w, lo4, hi4, acc);
    __syncthreads();

    // left = softmax over k: in-lane 16 + shfl_xor(16,32); per-lane l
    {
        const int l = 16 * w + lo4;
        float x[16];
        #pragma unroll
        for (int m = 0; m < 4; ++m)
            #pragma unroll
            for (int rg = 0; rg < 4; ++rg) x[4 * m + rg] = acc[m][rg] - av[4 * m + rg];
        float mx = max16(x);
        mx = fmaxf(mx, __shfl_xor(mx, 16));
        mx = fmaxf(mx, __shfl_xor(mx, 32));
        #pragma unroll
        for (int e = 0; e < 16; ++e) x[e] = __expf(x[e] - mx);
        float s = 0.f;
        #pragma unroll
        for (int e = 0; e < 16; ++e) s += x[e];
        s += __shfl_xor(s, 16);
        s += __shfl_xor(s, 32);
        const float inv = 1.f / s;
        #pragma unroll
        for (int m = 0; m < 4; ++m) {
            #pragma unroll
            for (int rg = 0; rg < 4; ++rg) {
                const float lv = x[4 * m + rg] * inv;
                ushort hh, ll; bfsplit(lv, hh, ll);
                const int kk = 16 * m + 4 * hi4 + rg;
                if (!LAST) { Bh[kk * 72 + l] = hh; Bl[kk * 72 + l] = ll; }  // left^T [k][l]
                else       { Bh[l * 72 + kk] = hh; Bl[l * 72 + kk] = ll; }  // left [l][k]
            }
        }
    }
    if (!LAST) scatter_tr(Ah, Al, r, c0, fq);      // q^T over dead q rows
    else       scatter_tr(Ah, Al, r, c0, fy);      // Y^T over dead q rows
    __syncthreads();

    if (!LAST) {
        f32x4 acc2[4] = {};
        f32x4 tacc = {};
        short8v onesb;
        #pragma unroll
        for (int e2 = 0; e2 < 8; ++e2) onesb[e2] = (lo4 == 0) ? (short)0x3F80 : (short)0;
        #pragma unroll
        for (int ks = 0; ks < 2; ++ks) {
            short8v ah = LD8(Bh, 16 * w + lo4, hi4 + 4 * ks);   // left^T rows (k)
            short8v al = LD8(Bl, 16 * w + lo4, hi4 + 4 * ks);
            MFMA(tacc, ah, onesb); MFMA(tacc, al, onesb);
            #pragma unroll
            for (int t = 0; t < 4; ++t) {
                short8v bh = LD8(Ah, 16 * t + lo4, hi4 + 4 * ks); // q^T rows (v)
                short8v bl = LD8(Al, 16 * t + lo4, hi4 + 4 * ks);
                MFMA(acc2[t], ah, bh); MFMA(acc2[t], ah, bl); MFMA(acc2[t], al, bh);
            }
        }
        __syncthreads();
        #pragma unroll
        for (int rr = 0; rr < 4; ++rr) {           // stage G f32 -> OSB; tau scatter
            const int kq = 16 * w + 4 * hi4 + rr;
            if (lo4 == 0) tauOut[((size_t)h * 64 + kq) * 64 + j] = tacc[rr];
            #pragma unroll
            for (int t = 0; t < 4; ++t)
                OSB[kq * 68 + 16 * t + lo4] = acc2[t][rr];
        }
        __syncthreads();
        flush_f32(OSB, Gout + ((size_t)h * 64 + j) * 4096, tid);
    } else {
        f32x4 acc2[4] = {};
        #pragma unroll
        for (int ks = 0; ks < 2; ++ks) {
            short8v ah = LD8(Bh, 16 * w + lo4, hi4 + 4 * ks);   // left rows (l)
            short8v al = LD8(Bl, 16 * w + lo4, hi4 + 4 * ks);
            #pragma unroll
            for (int t = 0; t < 4; ++t) {
                short8v bh = LD8(Ah, 16 * t + lo4, hi4 + 4 * ks); // Y^T rows (v)
                short8v bl = LD8(Al, 16 * t + lo4, hi4 + 4 * ks);
                MFMA(acc2[t], ah, bh); MFMA(acc2[t], ah, bl); MFMA(acc2[t], al, bh);
            }
        }
        __syncthreads();
        #pragma unroll
        for (int rr = 0; rr < 4; ++rr) {           // stage Z f32 -> OSB
            const int l = 16 * w + 4 * hi4 + rr;
            #pragma unroll
            for (int t = 0; t < 4; ++t) OSB[l * 68 + 16 * t + lo4] = acc2[t][rr];
        }
        __syncthreads();
        #pragma unroll
        for (int q = 0; q < 4; ++q) {              // 256-B chunk per 16-lane group
            const int l = (tid >> 4) + 16 * q;
            const int v4 = (tid & 15) * 4;
            float4 vv = *(const float4*)(OSB + l * 68 + v4);
            *(float4*)(Zout + (size_t)h * HEADQ + (size_t)l * 4096 + (size_t)j * 64 + v4) = vv;
        }
    }
}

} // namespace

extern "C" void kernel_launch(void* const* d_in, const int* in_sizes, int n_in,
                              void* d_out, int out_size, void* d_ws, size_t ws_size,
                              hipStream_t stream) {
    const float* Q = (const float*)d_in[0];
    const float* K = (const float*)d_in[1];
    const float* V = (const float*)d_in[2];
    float* out = (float*)d_out;

    char* ws = (char*)d_ws;
    const size_t MB = 1024 * 1024;
    float* G   = (float*)(ws);                  // 64 MiB (fallback: z staging)
    float* Hm  = (float*)(ws + 64 * MB);        // 64 MiB
    float* M   = (float*)(ws + 128 * MB);       //  1 MiB
    float* al  = (float*)(ws + 129 * MB);       //  1 MiB
    float* tau = (float*)(ws + 130 * MB);       //  1 MiB

    const bool bigws = ws_size >= (size_t)195 * MB;
    float* Ybuf = bigws ? (float*)(ws + 131 * MB) : out;   // Y staging
    float* Zdst = bigws ? out : G;

    dim3 blk(256), grid(HEADS * 64);

    kmean_kernel<<<dim3(1024), blk, 0, stream>>>(Q, M);
    bc_kernel<1, 0><<<grid, blk, 0, stream>>>(M, K, nullptr, nullptr, Hm, al, nullptr);
    da_kernel<0>   <<<grid, blk, 0, stream>>>(Q, Hm, al, nullptr, G, tau, nullptr);
    bc_kernel<0, 0><<<grid, blk, 0, stream>>>(G, K, nullptr, tau, Hm, al, nullptr);
    da_kernel<0>   <<<grid, blk, 0, stream>>>(Q, Hm, al, nullptr, G, tau, nullptr);
    bc_kernel<0, 1><<<grid, blk, 0, stream>>>(G, K, V, tau, Hm, al, Ybuf);
    da_kernel<1>   <<<grid, blk, 0, stream>>>(Q, Hm, al, Ybuf, nullptr, nullptr, Zdst);
    if (!bigws)
        hipMemcpyAsync(d_out, Zdst, MATF * sizeof(float), hipMemcpyDeviceToDevice, stream);
}

// Round 13
// 300.452 us; speedup vs baseline: 1.1145x; 1.0061x over previous
//
#include <hip/hip_runtime.h>

// SOBA-Monarch, B*H=64 heads, S=4096, D=64, nb=bs=64, pad=0, 3 steps.
// Round 13 = R12 + async staging: G/Hm/Y/M stored as pre-split hi/lo bf16
// ushort arrays in chunk-XOR-swizzled [64][64] tile images; consumers stage
// them via __builtin_amdgcn_global_load_lds (width 16, linear copy); LDS
// tiles are [64][64] XOR-swizzled (32 KB total). Arithmetic identical to R12.
// Layouts: G tiles (h,j)=[k][v] | Hm,Y tiles (h,k)=[j][v] | M tile (h)=[j][v]
//          alpha [h][j][k] f32 | tau [h][k][j] f32

namespace {

typedef __attribute__((ext_vector_type(8))) short short8v;
typedef __attribute__((ext_vector_type(4))) float f32x4;

constexpr int HEADS = 64;
constexpr size_t HEADQ = 262144;                 // 4096*64 per head
constexpr size_t MATF  = (size_t)HEADS * 262144;

#define MFMA(ACC, A, B) ACC = __builtin_amdgcn_mfma_f32_16x16x32_bf16(A, B, ACC, 0, 0, 0)

__device__ __forceinline__ void gload16(const ushort* g, ushort* l) {
    __builtin_amdgcn_global_load_lds(
        (const __attribute__((address_space(1))) void*)g,
        (__attribute__((address_space(3))) void*)l, 16, 0, 0);
}

// chunk-XOR swizzle inside a [64][64] ushort tile (8 chunks of 8 ushorts/row)
__device__ __forceinline__ int swz(int row, int col) {
    return row * 64 + (((col >> 3) ^ (row & 7)) << 3) + (col & 7);
}
__device__ __forceinline__ short8v ldx(const ushort* a, int row, int chunk) {
    return *(const short8v*)(a + row * 64 + ((chunk ^ (row & 7)) << 3));
}

__device__ __forceinline__ void bfsplit(float x, ushort& h, ushort& l) {
    uint u = __float_as_uint(x);
    uint hi = (u + 0x7FFFu + ((u >> 16) & 1u)) & 0xFFFF0000u;
    h = (ushort)(hi >> 16);
    l = (ushort)(__float_as_uint(x - __uint_as_float(hi)) >> 16);
}

struct Frag16 { short8v h0, h1, l0, l1; };

// f32 global (16 elems) -> split regs
__device__ __forceinline__ Frag16 split_load(const float* __restrict__ p, float s) {
    Frag16 f;
    #pragma unroll
    for (int q = 0; q < 4; ++q) {
        float4 a = *(const float4*)(p + 4 * q);
        float v[4] = {a.x * s, a.y * s, a.z * s, a.w * s};
        #pragma unroll
        for (int e = 0; e < 4; ++e) {
            ushort hh, ll; bfsplit(v[e], hh, ll);
            const int i = 4 * q + e;
            if (i < 8) { f.h0[i] = (short)hh; f.l0[i] = (short)ll; }
            else       { f.h1[i - 8] = (short)hh; f.l1[i - 8] = (short)ll; }
        }
    }
    return f;
}
__device__ __forceinline__ void store_rows(ushort* H, ushort* L, int r, int c0,
                                           const Frag16& f) {
    const int ch = c0 >> 3;
    const int o0 = r * 64 + ((ch ^ (r & 7)) << 3);
    const int o1 = r * 64 + (((ch + 1) ^ (r & 7)) << 3);
    *(short8v*)(H + o0) = f.h0; *(short8v*)(H + o1) = f.h1;
    *(short8v*)(L + o0) = f.l0; *(short8v*)(L + o1) = f.l1;
}
__device__ __forceinline__ void scatter_tr(ushort* H, ushort* L, int r, int c0,
                                           const Frag16& f) {
    #pragma unroll
    for (int e = 0; e < 8; ++e) {
        H[swz(c0 + e, r)] = (ushort)f.h0[e];
        L[swz(c0 + e, r)] = (ushort)f.l0[e];
    }
    #pragma unroll
    for (int e = 0; e < 8; ++e) {
        H[swz(c0 + 8 + e, r)] = (ushort)f.h1[e];
        L[swz(c0 + 8 + e, r)] = (ushort)f.l1[e];
    }
}

// linear flush of an 8KB (4096-ushort) swizzled tile image -> global
__device__ __forceinline__ void flush8k(const ushort* S, ushort* g, int tid) {
    *(short8v*)(g + tid * 8)        = *(const short8v*)(S + tid * 8);
    *(short8v*)(g + 2048 + tid * 8) = *(const short8v*)(S + 2048 + tid * 8);
}

__device__ __forceinline__ void mmstep(const ushort* AH, const ushort* AL,
                                       const ushort* BH, const ushort* BL,
                                       int w, int lo4, int hi4, f32x4 acc[4]) {
    #pragma unroll
    for (int ks = 0; ks < 2; ++ks) {
        short8v ah = ldx(AH, 16 * w + lo4, hi4 + 4 * ks);
        short8v al = ldx(AL, 16 * w + lo4, hi4 + 4 * ks);
        #pragma unroll
        for (int t = 0; t < 4; ++t) {
            short8v bh = ldx(BH, 16 * t + lo4, hi4 + 4 * ks);
            short8v bl = ldx(BL, 16 * t + lo4, hi4 + 4 * ks);
            MFMA(acc[t], ah, bh); MFMA(acc[t], ah, bl); MFMA(acc[t], al, bh);
        }
    }
}
// swapped: acc[m] = A-strip m (from B region) x B-strip w (from A region)
__device__ __forceinline__ void mmstep_swap(const ushort* AH, const ushort* AL,
                                            const ushort* BH, const ushort* BL,
                                            int w, int lo4, int hi4, f32x4 acc[4]) {
    #pragma unroll
    for (int ks = 0; ks < 2; ++ks) {
        short8v bh = ldx(AH, 16 * w + lo4, hi4 + 4 * ks);
        short8v bl = ldx(AL, 16 * w + lo4, hi4 + 4 * ks);
        #pragma unroll
        for (int m = 0; m < 4; ++m) {
            short8v ah = ldx(BH, 16 * m + lo4, hi4 + 4 * ks);
            short8v al = ldx(BL, 16 * m + lo4, hi4 + 4 * ks);
            MFMA(acc[m], ah, bh); MFMA(acc[m], ah, bl); MFMA(acc[m], al, bh);
        }
    }
}

__device__ __forceinline__ float max16(const float* x) {
    float a = fmaxf(fmaxf(x[0], x[1]), fmaxf(x[2], x[3]));
    float b = fmaxf(fmaxf(x[4], x[5]), fmaxf(x[6], x[7]));
    float c = fmaxf(fmaxf(x[8], x[9]), fmaxf(x[10], x[11]));
    float d = fmaxf(fmaxf(x[12], x[13]), fmaxf(x[14], x[15]));
    return fmaxf(fmaxf(a, b), fmaxf(c, d));
}

// M tile per h: [j][v] hi/lo, swizzled image
__global__ __launch_bounds__(256) void kmean_kernel(const float* __restrict__ Q,
                                                    ushort* __restrict__ Mh,
                                                    ushort* __restrict__ Ml) {
    const int wg = blockIdx.x;                      // 1024 WGs
    const int h  = wg >> 4;
    const int j  = ((wg & 15) << 2) + (threadIdx.x >> 6);
    const int v  = threadIdx.x & 63;
    const float* base = Q + (size_t)h * HEADQ + (size_t)j * 64 + v;
    float acc = 0.f;
    #pragma unroll
    for (int l = 0; l < 64; ++l) acc += base[(size_t)l * 4096];
    ushort hh, ll; bfsplit(acc * (1.0f / 512.0f), hh, ll);
    const int idx = swz(j, v);
    Mh[(size_t)h * 4096 + idx] = hh;
    Ml[(size_t)h * 4096 + idx] = ll;
}

// One WG (256T) per (h,k).
// MM1 (swapped): beta^T[i,j]; in-lane softmax over i; alpha via entropy identity
// MM2: Hm[j,v]=sum_i right[j,i]K[i,v];  LAST: Y[j,v]=sum_i right[j,i]V[i,v]
template<int FIRST, int LAST>
__global__ __launch_bounds__(256, 4) void bc_kernel(
    const ushort* __restrict__ Gh,    // FIRST: M tiles (h) ; else G tiles (h,j)=[k][v]
    const ushort* __restrict__ Gl,
    const float*  __restrict__ Kmat,
    const float*  __restrict__ Vmat,  // LAST only
    const float*  __restrict__ tauIn, // !FIRST, [h][k][j]
    ushort* __restrict__ Hmh,         // tiles (h,k)=[j][v]
    ushort* __restrict__ Hml,
    float*  __restrict__ alphaOut,    // [h][j][k]
    ushort* __restrict__ Yh,          // LAST only, tiles (h,k)=[j][v]
    ushort* __restrict__ Yl)
{
    __shared__ __align__(16) ushort SM[16384];     // 32768 B
    ushort* Ah = SM;          ushort* Al = SM + 4096;   // G rows -> right rows
    ushort* Bh = SM + 8192;   ushort* Bl = SM + 12288;  // K rows -> K^T -> V^T

    const int wg = blockIdx.x, h = wg >> 6, k = wg & 63;
    const int tid = threadIdx.x, r = tid & 63, c0 = (tid >> 6) << 4;
    const int w = tid >> 6, lo4 = tid & 15, hi4 = (tid >> 4) & 3;

    // async stage G (or M) -> A region, direct to LDS
    #pragma unroll
    for (int a = 0; a < 2; ++a) {
        const int o = a * 4096 + tid * 16;          // byte offset in 8KB image
        size_t src;
        if (FIRST) {
            src = (size_t)h * 4096 + (size_t)(o >> 1);        // linear copy
        } else {
            const int row = o >> 7, cd = (o >> 4) & 7;
            const int cu = cd ^ (row & 7);
            src = ((size_t)h * 64 + row) * 4096 + (size_t)k * 64
                + (size_t)((cu ^ (k & 7)) << 3);
        }
        gload16(Gh + src, (ushort*)((char*)Ah + o));
        gload16(Gl + src, (ushort*)((char*)Al + o));
    }
    // stage K rows -> B, keep regs for K^T scatter
    Frag16 fk = split_load(Kmat + (size_t)h * HEADQ + (size_t)k * 4096 + r * 64 + c0, 1.f);
    store_rows(Bh, Bl, r, c0, fk);
    Frag16 fv;
    if (LAST)
        fv = split_load(Vmat + (size_t)h * HEADQ + (size_t)k * 4096 + r * 64 + c0, 1.f);
    float tv = 1.f;
    if (!FIRST) tv = tauIn[((size_t)h * 64 + k) * 64 + 16 * w + lo4];
    __syncthreads();

    // MM1 swapped: acc[m][reg] = beta[i=16m+4hi4+reg][j=16w+lo4]
    f32x4 acc[4] = {};
    mmstep_swap(Ah, Al, Bh, Bl, w, lo4, hi4, acc);
    __syncthreads();

    // softmax over i (in-lane 16 + shfl 16,32); alpha via entropy identity
    {
        const int j = 16 * w + lo4;
        const bool tz = !(tv > 1e-8f);
        const float tvi = tz ? 1.f : 1.f / tv;
        float x[16];
        #pragma unroll
        for (int m = 0; m < 4; ++m)
            #pragma unroll
            for (int rg = 0; rg < 4; ++rg) x[4 * m + rg] = acc[m][rg] * tvi;
        float mx = max16(x);
        mx = fmaxf(mx, __shfl_xor(mx, 16));
        mx = fmaxf(mx, __shfl_xor(mx, 32));
        float ex[16], s = 0.f, p = 0.f;
        #pragma unroll
        for (int e = 0; e < 16; ++e) {
            ex[e] = __expf(x[e] - mx);
            s += ex[e];
            p = fmaf(ex[e], x[e], p);
        }
        s += __shfl_xor(s, 16);
        s += __shfl_xor(s, 32);
        p += __shfl_xor(p, 16);
        p += __shfl_xor(p, 32);
        const float inv = 1.f / s;
        const float ap = tz ? -4.1588830834f
                            : fmaf(p, inv, -mx - __logf(s));
        #pragma unroll
        for (int m = 0; m < 4; ++m) {
            #pragma unroll
            for (int rg = 0; rg < 4; ++rg) {
                const float rv = tz ? (1.f / 64.f) : ex[4 * m + rg] * inv;
                ushort hh, ll; bfsplit(rv, hh, ll);
                const int idx = swz(j, 16 * m + 4 * hi4 + rg);
                Ah[idx] = hh; Al[idx] = ll;          // right rows [j][i]
            }
        }
        if (hi4 == 0) alphaOut[((size_t)h * 64 + j) * 64 + k] = ap;
    }
    scatter_tr(Bh, Bl, r, c0, fk);                 // K^T over dead K rows
    __syncthreads();

    f32x4 acc2[4] = {};
    mmstep(Ah, Al, Bh, Bl, w, lo4, hi4, acc2);     // Hm: A=right rows, B=K^T
    const size_t ob = ((size_t)h * 64 + k) * 4096;
    if (!LAST) {
        __syncthreads();
        #pragma unroll
        for (int rr = 0; rr < 4; ++rr) {           // stage Hm split -> B (swz image)
            const int j = 16 * w + 4 * hi4 + rr;
            #pragma unroll
            for (int t = 0; t < 4; ++t) {
                ushort hh, ll; bfsplit(acc2[t][rr], hh, ll);
                const int idx = swz(j, 16 * t + lo4);
                Bh[idx] = hh; Bl[idx] = ll;
            }
        }
        __syncthreads();
        flush8k(Bh, Hmh + ob, tid);
        flush8k(Bl, Hml + ob, tid);
    } else {
        __syncthreads();
        scatter_tr(Bh, Bl, r, c0, fv);             // V^T over dead K^T
        __syncthreads();
        f32x4 acc3[4] = {};
        mmstep(Ah, Al, Bh, Bl, w, lo4, hi4, acc3); // Y: A=right, B=V^T
        __syncthreads();
        #pragma unroll
        for (int rr = 0; rr < 4; ++rr) {           // Hm -> A image, Y -> B image
            const int j = 16 * w + 4 * hi4 + rr;
            #pragma unroll
            for (int t = 0; t < 4; ++t) {
                const int idx = swz(j, 16 * t + lo4);
                ushort hh, ll;
                bfsplit(acc2[t][rr], hh, ll);
                Ah[idx] = hh; Al[idx] = ll;
                bfsplit(acc3[t][rr], hh, ll);
                Bh[idx] = hh; Bl[idx] = ll;
            }
        }
        __syncthreads();
        flush8k(Ah, Hmh + ob, tid);
        flush8k(Al, Hml + ob, tid);
        flush8k(Bh, Yh + ob, tid);
        flush8k(Bl, Yl + ob, tid);
    }
}

// One WG per (h,j).
// MM1 (swapped): beta2^T[k,l]; in-lane softmax over k
// !LAST: G[k,v]=sum_l left[l,k]q[l,v] (swz image flush); tau via ones-MFMA
//  LAST: Z[l,v]=sum_k left[l,k]Y[k,v] (f32 staged)
template<int LAST>
__global__ __launch_bounds__(256, 4) void da_kernel(
    const float*  __restrict__ Q,
    const ushort* __restrict__ Hmh,   // tiles (h,k)=[j][v]
    const ushort* __restrict__ Hml,
    const float*  __restrict__ alphaIn, // [h][j][k]
    const ushort* __restrict__ Yh,    // LAST only, tiles (h,k)=[j][v]
    const ushort* __restrict__ Yl,
    ushort* __restrict__ Goh,         // !LAST, tiles (h,j)=[k][v]
    ushort* __restrict__ Gol,
    float*  __restrict__ tauOut,      // !LAST, [h][k][j]
    float*  __restrict__ Zout)        // LAST
{
    __shared__ __align__(16) ushort SM[16384];
    ushort* Ah = SM;          ushort* Al = SM + 4096;   // q rows -> q^T / Y^T
    ushort* Bh = SM + 8192;   ushort* Bl = SM + 12288;  // Hm rows -> left
    float* OSZ = (float*)(SM + 8192);                   // 16KB f32 [64][64] (LAST)

    const int wg = blockIdx.x, h = wg >> 6, j = wg & 63;
    const int tid = threadIdx.x, r = tid & 63, c0 = (tid >> 6) << 4;
    const int w = tid >> 6, lo4 = tid & 15, hi4 = (tid >> 4) & 3;

    // async stage Hm rows (row kd <- tile (h,kd) row j) -> B region
    #pragma unroll
    for (int a = 0; a < 2; ++a) {
        const int o = a * 4096 + tid * 16;
        const int kd = o >> 7, cd = (o >> 4) & 7;
        const int cu = cd ^ (kd & 7);
        const size_t src = ((size_t)h * 64 + kd) * 4096 + (size_t)j * 64
                         + (size_t)((cu ^ (j & 7)) << 3);
        gload16(Hmh + src, (ushort*)((char*)Bh + o));
        gload16(Hml + src, (ushort*)((char*)Bl + o));
    }
    // stage q (x0.125) -> A, keep regs for q^T
    Frag16 fq = split_load(Q + (size_t)h * HEADQ + (size_t)r * 4096 + (size_t)j * 64 + c0,
                           0.125f);
    store_rows(Ah, Al, r, c0, fq);
    Frag16 fy;
    if (LAST) {                                    // Y tile (h, r) row j -> regs
        const size_t yb = ((size_t)h * 64 + r) * 4096 + (size_t)j * 64;
        const int ch = c0 >> 3;
        const int sA = ((ch ^ (j & 7)) << 3), sB = (((ch + 1) ^ (j & 7)) << 3);
        fy.h0 = *(const short8v*)(Yh + yb + sA);
        fy.h1 = *(const short8v*)(Yh + yb + sB);
        fy.l0 = *(const short8v*)(Yl + yb + sA);
        fy.l1 = *(const short8v*)(Yl + yb + sB);
    }
    float av[16];
    {
        const float* ap0 = alphaIn + ((size_t)h * 64 + j) * 64 + 4 * hi4;
        #pragma unroll
        for (int m = 0; m < 4; ++m)
            #pragma unroll
            for (int rg = 0; rg < 4; ++rg) av[4 * m + rg] = ap0[16 * m + rg];
    }
    __syncthreads();

    // MM1 swapped: acc[m][rg] = beta2[k=16m+4hi4+rg][l=16w+lo4]
    f32x4 acc[4] = {};
    mmstep_swap(Ah, Al, Bh, Bl, w, lo4, hi4, acc);
    __syncthreads();

    // left = softmax over k: in-lane 16 + shfl(16,32); per-lane l
    {
        const int l = 16 * w + lo4;
        float x[16];
        #pragma unroll
        for (int m = 0; m < 4; ++m)
            #pragma unroll
            for (int rg = 0; rg < 4; ++rg) x[4 * m + rg] = acc[m][rg] - av[4 * m + rg];
        float mx = max16(x);
        mx = fmaxf(mx, __shfl_xor(mx, 16));
        mx = fmaxf(mx, __shfl_xor(mx, 32));
        #pragma unroll
        for (int e = 0; e < 16; ++e) x[e] = __expf(x[e] - mx);
        float s = 0.f;
        #pragma unroll
        for (int e = 0; e < 16; ++e) s += x[e];
        s += __shfl_xor(s, 16);
        s += __shfl_xor(s, 32);
        const float inv = 1.f / s;
        #pragma unroll
        for (int m = 0; m < 4; ++m) {
            #pragma unroll
            for (int rg = 0; rg < 4; ++rg) {
                const float lv = x[4 * m + rg] * inv;
                ushort hh, ll; bfsplit(lv, hh, ll);
                const int kk = 16 * m + 4 * hi4 + rg;
                const int idx = LAST ? swz(l, kk) : swz(kk, l);
                Bh[idx] = hh; Bl[idx] = ll;
            }
        }
    }
    if (!LAST) scatter_tr(Ah, Al, r, c0, fq);      // q^T over dead q rows
    else       scatter_tr(Ah, Al, r, c0, fy);      // Y^T over dead q rows
    __syncthreads();

    if (!LAST) {
        f32x4 acc2[4] = {};
        f32x4 tacc = {};
        short8v onesb;
        #pragma unroll
        for (int e2 = 0; e2 < 8; ++e2) onesb[e2] = (lo4 == 0) ? (short)0x3F80 : (short)0;
        #pragma unroll
        for (int ks = 0; ks < 2; ++ks) {
            short8v ah = ldx(Bh, 16 * w + lo4, hi4 + 4 * ks);   // left^T rows (k)
            short8v al = ldx(Bl, 16 * w + lo4, hi4 + 4 * ks);
            MFMA(tacc, ah, onesb); MFMA(tacc, al, onesb);
            #pragma unroll
            for (int t = 0; t < 4; ++t) {
                short8v bh = ldx(Ah, 16 * t + lo4, hi4 + 4 * ks); // q^T rows (v)
                short8v bl = ldx(Al, 16 * t + lo4, hi4 + 4 * ks);
                MFMA(acc2[t], ah, bh); MFMA(acc2[t], ah, bl); MFMA(acc2[t], al, bh);
            }
        }
        __syncthreads();
        #pragma unroll
        for (int rr = 0; rr < 4; ++rr) {           // stage G split -> B image; tau
            const int kq = 16 * w + 4 * hi4 + rr;
            if (lo4 == 0) tauOut[((size_t)h * 64 + kq) * 64 + j] = tacc[rr];
            #pragma unroll
            for (int t = 0; t < 4; ++t) {
                ushort hh, ll; bfsplit(acc2[t][rr], hh, ll);
                const int idx = swz(kq, 16 * t + lo4);
                Bh[idx] = hh; Bl[idx] = ll;
            }
        }
        __syncthreads();
        const size_t ob = ((size_t)h * 64 + j) * 4096;
        flush8k(Bh, Goh + ob, tid);
        flush8k(Bl, Gol + ob, tid);
    } else {
        f32x4 acc2[4] = {};
        #pragma unroll
        for (int ks = 0; ks < 2; ++ks) {
            short8v ah = ldx(Bh, 16 * w + lo4, hi4 + 4 * ks);   // left rows (l)
            short8v al = ldx(Bl, 16 * w + lo4, hi4 + 4 * ks);
            #pragma unroll
            for (int t = 0; t < 4; ++t) {
                short8v bh = ldx(Ah, 16 * t + lo4, hi4 + 4 * ks); // Y^T rows (v)
                short8v bl = ldx(Al, 16 * t + lo4, hi4 + 4 * ks);
                MFMA(acc2[t], ah, bh); MFMA(acc2[t], ah, bl); MFMA(acc2[t], al, bh);
            }
        }
        __syncthreads();
        #pragma unroll
        for (int rr = 0; rr < 4; ++rr) {           // stage Z f32 -> B region [64][64]
            const int l = 16 * w + 4 * hi4 + rr;
            #pragma unroll
            for (int t = 0; t < 4; ++t) OSZ[l * 64 + 16 * t + lo4] = acc2[t][rr];
        }
        __syncthreads();
        #pragma unroll
        for (int q = 0; q < 4; ++q) {              // 256-B chunk per 16-lane group
            const int lrow = (tid >> 4) + 16 * q;
            const int v4 = (tid & 15) * 4;
            float4 vv = *(const float4*)(OSZ + lrow * 64 + v4);
            *(float4*)(Zout + (size_t)h * HEADQ + (size_t)lrow * 4096 + (size_t)j * 64 + v4) = vv;
        }
    }
}

} // namespace

extern "C" void kernel_launch(void* const* d_in, const int* in_sizes, int n_in,
                              void* d_out, int out_size, void* d_ws, size_t ws_size,
                              hipStream_t stream) {
    const float* Q = (const float*)d_in[0];
    const float* K = (const float*)d_in[1];
    const float* V = (const float*)d_in[2];
    float* out = (float*)d_out;

    char* ws = (char*)d_ws;
    const size_t MB = 1024 * 1024;
    ushort* Gh  = (ushort*)(ws);                  // 32 MiB
    ushort* Gl  = (ushort*)(ws + 32 * MB);        // 32 MiB
    ushort* Hmh = (ushort*)(ws + 64 * MB);        // 32 MiB
    ushort* Hml = (ushort*)(ws + 96 * MB);        // 32 MiB
    ushort* Mh  = (ushort*)(ws + 128 * MB);       // 0.5 MiB
    ushort* Ml  = (ushort*)(ws + 128 * MB + 512 * 1024);
    float*  al  = (float*)(ws + 129 * MB);        // 1 MiB
    float*  tau = (float*)(ws + 130 * MB);        // 1 MiB

    const bool bigws = ws_size >= (size_t)195 * MB;
    ushort* Yh = bigws ? (ushort*)(ws + 131 * MB) : (ushort*)out;
    ushort* Yl = bigws ? (ushort*)(ws + 163 * MB) : (ushort*)out + 16777216;
    float*  Zdst = bigws ? out : (float*)ws;      // !bigws: Z over G region

    dim3 blk(256), grid(HEADS * 64);

    kmean_kernel<<<dim3(1024), blk, 0, stream>>>(Q, Mh, Ml);
    bc_kernel<1, 0><<<grid, blk, 0, stream>>>(Mh, Ml, K, nullptr, nullptr,
                                              Hmh, Hml, al, nullptr, nullptr);
    da_kernel<0>   <<<grid, blk, 0, stream>>>(Q, Hmh, Hml, al, nullptr, nullptr,
                                              Gh, Gl, tau, nullptr);
    bc_kernel<0, 0><<<grid, blk, 0, stream>>>(Gh, Gl, K, nullptr, tau,
                                              Hmh, Hml, al, nullptr, nullptr);
    da_kernel<0>   <<<grid, blk, 0, stream>>>(Q, Hmh, Hml, al, nullptr, nullptr,
                                              Gh, Gl, tau, nullptr);
    bc_kernel<0, 1><<<grid, blk, 0, stream>>>(Gh, Gl, K, V, tau,
                                              Hmh, Hml, al, Yh, Yl);
    da_kernel<1>   <<<grid, blk, 0, stream>>>(Q, Hmh, Hml, al, Yh, Yl,
                                              nullptr, nullptr, nullptr, Zdst);
    if (!bigws)
        hipMemcpyAsync(d_out, Zdst, MATF * sizeof(float), hipMemcpyDeviceToDevice, stream);
}